// Round 15
// baseline (3779.176 us; speedup 1.0000x reference)
//
#include <hip/hip_runtime.h>

#define NP 1600000
#define NNODES 50000
#define NEDGES 100000

typedef short bf16x8 __attribute__((ext_vector_type(8)));
typedef short short4b __attribute__((ext_vector_type(4)));
typedef float f32x4 __attribute__((ext_vector_type(4)));
typedef unsigned short ushort_t;

static __device__ __forceinline__ ushort_t f2bf_rne(float f) {
    __bf16 b = (__bf16)f;
    return __builtin_bit_cast(ushort_t, b);
}
static __device__ __forceinline__ float bf2f(ushort_t h) {
    union { float f; unsigned int u; } v; v.u = ((unsigned int)h) << 16;
    return v.f;
}
static __device__ __forceinline__ void addbf8(float* a, uint4 u) {
    unsigned int uu[4] = {u.x, u.y, u.z, u.w};
#pragma unroll
    for (int q = 0; q < 4; ++q) {
        union { float f; unsigned int v; } lo, hi;
        lo.v = uu[q] << 16; hi.v = uu[q] & 0xffff0000u;
        a[2 * q]     += lo.f;
        a[2 * q + 1] += hi.f;
    }
}

static __device__ __forceinline__ void gload_lds16(const void* g, void* lds) {
    __builtin_amdgcn_global_load_lds(
        (const __attribute__((address_space(1))) unsigned int*)g,
        (__attribute__((address_space(3))) unsigned int*)lds, 16, 0, 0);
}

// ---------------- WIDE single-bf16 MFMA GEMM: BM=128, BN=256, 512 thr -------
// Same 2-barrier schedule as the proven narrow kernel; 8 waves (2 row x 4 col
// of 64x64) -> 128 MFMA per block-tile vs 64, amortizing the per-tile
// barrier+drain latency 2x. LDS 48.3KB -> 3 blocks/CU (24 waves).
// A [M,K]: f32 (in-kernel cvt, AF32) or bf16 (gload_lds). B^T [N,K] bf16.
// EPI: 0 f32 out, 1 bf16 out.
template<bool AF32, bool DORELU, int EPI>
__global__ __launch_bounds__(512, 6) void gemm_wide(
    const float* __restrict__ Af, const ushort_t* __restrict__ Ab,
    const ushort_t* __restrict__ Bth,
    const float* __restrict__ bias,
    float* __restrict__ Cf, ushort_t* __restrict__ Cb,
    int M, int N, int K)
{
    __shared__ ushort_t As [4][129][8];   // 128 A rows
    __shared__ ushort_t BsH[4][257][8];   // 256 B rows (N-cols)

    const int tid = threadIdx.x;
    const int wid = tid >> 6;             // 0..7
    const int lane = tid & 63;

    // bijective XCD-chunked swizzle
    const int nwg = gridDim.x * gridDim.y;
    const int wg  = blockIdx.y * gridDim.x + blockIdx.x;
    const int q = nwg >> 3, r = nwg & 7;
    const int xcd = wg & 7, loc = wg >> 3;
    const int swz = (xcd < r) ? (xcd * (q + 1) + loc)
                              : (r * (q + 1) + (xcd - r) * q + loc);
    const int bn0 = (int)(swz % gridDim.x) * 256;
    const int bm0 = (int)(swz / gridDim.x) * 128;

    const int wrow0 = (wid >> 2) * 64;    // 0 or 64
    const int wcol0 = (wid & 3) * 64;     // 0..192
    const int kgl = lane >> 4;
    const int r16 = lane & 15;

    f32x4 acc[4][4];
#pragma unroll
    for (int i = 0; i < 4; ++i)
#pragma unroll
        for (int j = 0; j < 4; ++j) acc[i][j] = (f32x4)0.f;

    const int nk = K >> 5;

    // AF32 A-staging geometry: 128 rows x 8 quads, 512 threads -> 2 quads each
    const int a_kq   = tid & 7;
    const int a_row0 = tid >> 3;          // 0..63; rows = a_row0 + cch*64
    const float* aBase[2];
    float4 aPre[2];
    if constexpr (AF32) {
#pragma unroll
        for (int cch = 0; cch < 2; ++cch) {
            int row = cch * 64 + a_row0;
            int rr = bm0 + row; if (rr > M - 1) rr = M - 1;
            aBase[cch] = Af + (size_t)rr * K + a_kq * 4;
            aPre[cch] = *(const float4*)(aBase[cch]);   // tile 0
        }
    }

    for (int kt = 0; kt < nk; ++kt) {
        __syncthreads();
        // ---- stage B: 256 rows x 4 kg-planes; wave (wid&3)=plane,
        //      (wid>>2)*128 + h*64 = row block ----
#pragma unroll
        for (int h = 0; h < 2; ++h) {
            int row0 = (wid >> 2) * 128 + h * 64;
            int cc = bn0 + row0 + lane;
            gload_lds16(Bth + (size_t)cc * K + kt * 32 + (wid & 3) * 8,
                        &BsH[wid & 3][row0][0]);
        }
        // ---- stage A ----
        if constexpr (AF32) {
#pragma unroll
            for (int cch = 0; cch < 2; ++cch) {
                int row = cch * 64 + a_row0;
                float4 v = aPre[cch];
                short4b hi;
                hi[0] = (short)f2bf_rne(v.x); hi[1] = (short)f2bf_rne(v.y);
                hi[2] = (short)f2bf_rne(v.z); hi[3] = (short)f2bf_rne(v.w);
                int kg = a_kq >> 1, j0 = (a_kq & 1) * 4;
                *(short4b*)&As[kg][row][j0] = hi;
            }
        } else {
            // 128 rows x 4 planes, 8 waves -> 1 issue per wave
            int rr = bm0 + (wid >> 2) * 64 + lane; if (rr > M - 1) rr = M - 1;
            gload_lds16(Ab + (size_t)rr * K + kt * 32 + (wid & 3) * 8,
                        &As[wid & 3][(wid >> 2) * 64][0]);
        }
        __syncthreads();

        // issue next A f32 loads NOW; latency hides under MFMA
        if constexpr (AF32) {
            if (kt + 1 < nk) {
#pragma unroll
                for (int cch = 0; cch < 2; ++cch)
                    aPre[cch] = *(const float4*)(aBase[cch] + (kt + 1) * 32);
            }
        }

        bf16x8 ah[4], bh[4];
#pragma unroll
        for (int mi = 0; mi < 4; ++mi)
            ah[mi] = *(const bf16x8*)&As[kgl][wrow0 + mi * 16 + r16][0];
#pragma unroll
        for (int ni = 0; ni < 4; ++ni)
            bh[ni] = *(const bf16x8*)&BsH[kgl][wcol0 + ni * 16 + r16][0];
#pragma unroll
        for (int mi = 0; mi < 4; ++mi)
#pragma unroll
            for (int ni = 0; ni < 4; ++ni)
                acc[mi][ni] = __builtin_amdgcn_mfma_f32_16x16x32_bf16(ah[mi], bh[ni], acc[mi][ni], 0, 0, 0);
    }

    // ---- epilogue: C/D layout col=lane&15 (N), row=(lane>>4)*4+reg (M) ----
    const int rg4 = (lane >> 4) * 4;
#pragma unroll
    for (int ni = 0; ni < 4; ++ni) {
        int gcol = bn0 + wcol0 + ni * 16 + r16;
        float bb = bias[gcol];
#pragma unroll
        for (int mi = 0; mi < 4; ++mi)
#pragma unroll
            for (int rg = 0; rg < 4; ++rg) {
                int grow = bm0 + wrow0 + mi * 16 + rg4 + rg;
                if (grow < M) {
                    float v = acc[mi][ni][rg] + bb;
                    if constexpr (DORELU) v = fmaxf(v, 0.f);
                    if constexpr (EPI == 0) Cf[(size_t)grow * N + gcol] = v;
                    else                    Cb[(size_t)grow * N + gcol] = f2bf_rne(v);
                }
            }
    }
}

// ---------------- narrow kernel (BN=128) — kept for Gt2 (N=128) -------------
template<bool AF32, bool DORELU, int EPI>
__global__ __launch_bounds__(256, 3) void gemm_bf1(
    const float* __restrict__ Af, const ushort_t* __restrict__ Ab,
    const ushort_t* __restrict__ Bth,
    const float* __restrict__ bias,
    float* __restrict__ Cf, ushort_t* __restrict__ Cb,
    int M, int N, int K)
{
    __shared__ ushort_t As [4][129][8];
    __shared__ ushort_t BsH[4][129][8];

    const int tid = threadIdx.x;
    const int wid = tid >> 6;
    const int lane = tid & 63;

    const int nwg = gridDim.x * gridDim.y;
    const int wg  = blockIdx.y * gridDim.x + blockIdx.x;
    const int q = nwg >> 3, r = nwg & 7;
    const int xcd = wg & 7, loc = wg >> 3;
    const int swz = (xcd < r) ? (xcd * (q + 1) + loc)
                              : (r * (q + 1) + (xcd - r) * q + loc);
    const int bn0 = (int)(swz % gridDim.x) * 128;
    const int bm0 = (int)(swz / gridDim.x) * 128;

    const int wrow0 = (wid >> 1) * 64;
    const int wcol0 = (wid & 1) * 64;
    const int kgl = lane >> 4;
    const int r16 = lane & 15;

    f32x4 acc[4][4];
#pragma unroll
    for (int i = 0; i < 4; ++i)
#pragma unroll
        for (int j = 0; j < 4; ++j) acc[i][j] = (f32x4)0.f;

    const int nk = K >> 5;

    const int a_kq   = tid & 7;
    const int a_row0 = tid >> 3;
    const float* aBase[4];
    float4 aPre[4];
    if constexpr (AF32) {
#pragma unroll
        for (int cch = 0; cch < 4; ++cch) {
            int row = cch * 32 + a_row0;
            int rr = bm0 + row; if (rr > M - 1) rr = M - 1;
            aBase[cch] = Af + (size_t)rr * K + a_kq * 4;
            aPre[cch] = *(const float4*)(aBase[cch]);
        }
    }

    for (int kt = 0; kt < nk; ++kt) {
        __syncthreads();
#pragma unroll
        for (int h = 0; h < 2; ++h) {
            int cc = bn0 + h * 64 + lane;
            gload_lds16(Bth + (size_t)cc * K + kt * 32 + wid * 8,
                        &BsH[wid][h * 64][0]);
        }
        if constexpr (AF32) {
#pragma unroll
            for (int cch = 0; cch < 4; ++cch) {
                int row = cch * 32 + a_row0;
                float4 v = aPre[cch];
                short4b hi;
                hi[0] = (short)f2bf_rne(v.x); hi[1] = (short)f2bf_rne(v.y);
                hi[2] = (short)f2bf_rne(v.z); hi[3] = (short)f2bf_rne(v.w);
                int kg = a_kq >> 1, j0 = (a_kq & 1) * 4;
                *(short4b*)&As[kg][row][j0] = hi;
            }
        } else {
#pragma unroll
            for (int h = 0; h < 2; ++h) {
                int rr = bm0 + h * 64 + lane; if (rr > M - 1) rr = M - 1;
                gload_lds16(Ab + (size_t)rr * K + kt * 32 + wid * 8,
                            &As[wid][h * 64][0]);
            }
        }
        __syncthreads();

        if constexpr (AF32) {
            if (kt + 1 < nk) {
#pragma unroll
                for (int cch = 0; cch < 4; ++cch)
                    aPre[cch] = *(const float4*)(aBase[cch] + (kt + 1) * 32);
            }
        }

        bf16x8 ah[4], bh[4];
#pragma unroll
        for (int mi = 0; mi < 4; ++mi)
            ah[mi] = *(const bf16x8*)&As[kgl][wrow0 + mi * 16 + r16][0];
#pragma unroll
        for (int ni = 0; ni < 4; ++ni)
            bh[ni] = *(const bf16x8*)&BsH[kgl][wcol0 + ni * 16 + r16][0];
#pragma unroll
        for (int mi = 0; mi < 4; ++mi)
#pragma unroll
            for (int ni = 0; ni < 4; ++ni)
                acc[mi][ni] = __builtin_amdgcn_mfma_f32_16x16x32_bf16(ah[mi], bh[ni], acc[mi][ni], 0, 0, 0);
    }

    const int rg4 = (lane >> 4) * 4;
#pragma unroll
    for (int ni = 0; ni < 4; ++ni) {
        int gcol = bn0 + wcol0 + ni * 16 + r16;
        float bb = bias[gcol];
#pragma unroll
        for (int mi = 0; mi < 4; ++mi)
#pragma unroll
            for (int rg = 0; rg < 4; ++rg) {
                int grow = bm0 + wrow0 + mi * 16 + rg4 + rg;
                if (grow < M) {
                    float v = acc[mi][ni][rg] + bb;
                    if constexpr (DORELU) v = fmaxf(v, 0.f);
                    if constexpr (EPI == 0) Cf[(size_t)grow * N + gcol] = v;
                    else                    Cb[(size_t)grow * N + gcol] = f2bf_rne(v);
                }
            }
    }
}

// ------- fused prologue: weight transpose (single bf16) + CSR pass 1 -------
__global__ __launch_bounds__(256) void prep_csr(
    const float* __restrict__ W0, const float* __restrict__ W1,
    const float* __restrict__ W2, const float* __restrict__ Wt1,
    const float* __restrict__ Wt2,
    ushort_t* __restrict__ W0t, ushort_t* __restrict__ W1t,
    ushort_t* __restrict__ W2t, ushort_t* __restrict__ Wt1t,
    ushort_t* __restrict__ Wt2t,
    const int* __restrict__ ePos, const int* __restrict__ eNeg,
    const int* __restrict__ vPos, const int* __restrict__ vNeg,
    int* __restrict__ e_off, int* __restrict__ v_cnt)
{
    const int bsel = blockIdx.x;
    if (bsel >= 2080) {
        const int rel = bsel - 2080;
        const int sign = rel >> 10;
        const int* e_idx = sign ? eNeg : ePos;
        const int* v_idx = sign ? vNeg : vPos;
        int* o  = e_off + sign * (NEDGES + 1);
        int* vc = v_cnt + sign * NNODES;
        int i = (rel & 1023) * 256 + threadIdx.x;
        const int stride = 1024 * 256;
        for (; i < NP; i += stride) {
            int cur = e_idx[i];
            int prev = (i > 0) ? e_idx[i - 1] : -1;
            for (int e = prev + 1; e <= cur; ++e) o[e] = i;
            if (i == NP - 1)
                for (int e = cur + 1; e <= NEDGES; ++e) o[e] = NP;
            atomicAdd(&vc[v_idx[i]], 1);
        }
        return;
    }
    const float* W; ushort_t* H; int K, N, nx, rel;
    if (bsel < 1408)      { W = W0;  H = W0t;  K = 2816; N = 512; nx = 16; rel = bsel; }
    else if (bsel < 1664) { W = W1;  H = W1t;  K = 512;  N = 512; nx = 16; rel = bsel - 1408; }
    else if (bsel < 1920) { W = W2;  H = W2t;  K = 512;  N = 512; nx = 16; rel = bsel - 1664; }
    else if (bsel < 2048) { W = Wt1; H = Wt1t; K = 512;  N = 256; nx = 8;  rel = bsel - 1920; }
    else                  { W = Wt2; H = Wt2t; K = 256;  N = 128; nx = 4;  rel = bsel - 2048; }
    const int n0 = (rel % nx) * 32, k0 = (rel / nx) * 32;

    __shared__ float T[32][33];
    const int c = threadIdx.x & 31, r8 = threadIdx.x >> 5;
#pragma unroll
    for (int i = 0; i < 4; ++i)
        T[r8 + i * 8][c] = W[(size_t)(k0 + r8 + i * 8) * N + n0 + c];
    __syncthreads();
#pragma unroll
    for (int i = 0; i < 4; ++i) {
        int nr = r8 + i * 8;
        H[(size_t)(n0 + nr) * K + k0 + c] = f2bf_rne(T[c][nr]);
    }
}

__global__ __launch_bounds__(1024) void exscan2(const int* __restrict__ cnt,
                                                int* __restrict__ off)
{
    const int sign = blockIdx.x;
    const int* c = cnt + sign * NNODES;
    int* o = off + sign * (NNODES + 1);
    __shared__ int sums[1024];
    const int t = threadIdx.x;
    const int per = (NNODES + 1023) >> 10;
    const int b = t * per;
    const int e = min(b + per, NNODES);
    int s = 0;
    for (int i = b; i < e; ++i) s += c[i];
    sums[t] = s;
    __syncthreads();
    for (int d = 1; d < 1024; d <<= 1) {
        int v = (t >= d) ? sums[t - d] : 0;
        __syncthreads();
        sums[t] += v;
        __syncthreads();
    }
    int run = (t > 0) ? sums[t - 1] : 0;
    for (int i = b; i < e; ++i) { o[i] = run; run += c[i]; }
    if (t == 1023) o[NNODES] = run;
}

__global__ void scatter_both(const int* __restrict__ vPos, const int* __restrict__ vNeg,
                             const int* __restrict__ ePos, const int* __restrict__ eNeg,
                             const int* __restrict__ v_off, int* __restrict__ v_cnt,
                             int* __restrict__ e_by_v)
{
    const int sign = blockIdx.y;
    const int* v_idx = sign ? vNeg : vPos;
    const int* e_idx = sign ? eNeg : ePos;
    const int* vo = v_off + sign * (NNODES + 1);
    int* vc = v_cnt + sign * NNODES;
    int* ebv = e_by_v + sign * NP;
    int i = blockIdx.x * blockDim.x + threadIdx.x;
    int stride = gridDim.x * blockDim.x;
    for (; i < NP; i += stride) {
        int v = v_idx[i];
        int pos = atomicSub(&vc[v], 1) - 1;
        ebv[vo[v] + pos] = e_idx[i];
    }
}

// ---------------- segment mean, dual-sign, 16B/lane, 4-wide gather ----------
// EPI: 0 f32 out, 1 bf16 out, 3 f32 out + bf16 shadow.  Vectorized stores.
template<bool SRCBF, int C, bool DORELU, int EPI>
__global__ __launch_bounds__(256) void seg_mean2(
    const void* __restrict__ src, long long src_stride,
    const int* __restrict__ idx0, const int* __restrict__ idx1,
    const int* __restrict__ off_base, int off_stride,
    float* __restrict__ dstf, long long dstf_stride,
    ushort_t* __restrict__ dB, long long dB_stride,
    int nseg)
{
    constexpr int ES  = SRCBF ? 2 : 4;
    constexpr int LPR = (C * ES) / 16;
    constexpr int MPI = 64 / LPR;
    constexpr int CPL = 16 / ES;

    const int sign = blockIdx.y;
    const int* idx = sign ? idx1 : idx0;
    const int* off = off_base + (size_t)sign * off_stride;

    const int wave = threadIdx.x >> 6, lane = threadIdx.x & 63;
    const int s = blockIdx.x * 4 + wave;
    if (s >= nseg) return;
    const int b = off[s], e = off[s + 1];
    const int sub = lane / LPR;
    const int cbase = (lane % LPR) * CPL;

    float a0[CPL], a1[CPL], a2[CPL], a3[CPL];
#pragma unroll
    for (int k = 0; k < CPL; ++k) { a0[k] = 0.f; a1[k] = 0.f; a2[k] = 0.f; a3[k] = 0.f; }

    int j = b + sub;
    if constexpr (SRCBF) {
        const ushort_t* sp = (const ushort_t*)src + (size_t)sign * src_stride;
        for (; j + 3 * MPI < e; j += 4 * MPI) {
            int i0 = idx[j], i1 = idx[j + MPI], i2 = idx[j + 2 * MPI], i3 = idx[j + 3 * MPI];
            uint4 u0 = *(const uint4*)(sp + (size_t)i0 * C + cbase);
            uint4 u1 = *(const uint4*)(sp + (size_t)i1 * C + cbase);
            uint4 u2 = *(const uint4*)(sp + (size_t)i2 * C + cbase);
            uint4 u3 = *(const uint4*)(sp + (size_t)i3 * C + cbase);
            addbf8(a0, u0); addbf8(a1, u1); addbf8(a2, u2); addbf8(a3, u3);
        }
        for (; j < e; j += MPI) {
            uint4 u = *(const uint4*)(sp + (size_t)idx[j] * C + cbase);
            addbf8(a0, u);
        }
    } else {
        const float* sp = (const float*)src + (size_t)sign * src_stride;
        for (; j + 3 * MPI < e; j += 4 * MPI) {
            int i0 = idx[j], i1 = idx[j + MPI], i2 = idx[j + 2 * MPI], i3 = idx[j + 3 * MPI];
            float4 v0 = *(const float4*)(sp + (size_t)i0 * C + cbase);
            float4 v1 = *(const float4*)(sp + (size_t)i1 * C + cbase);
            float4 v2 = *(const float4*)(sp + (size_t)i2 * C + cbase);
            float4 v3 = *(const float4*)(sp + (size_t)i3 * C + cbase);
            a0[0] += v0.x; a0[1] += v0.y; a0[2] += v0.z; a0[3] += v0.w;
            a1[0] += v1.x; a1[1] += v1.y; a1[2] += v1.z; a1[3] += v1.w;
            a2[0] += v2.x; a2[1] += v2.y; a2[2] += v2.z; a2[3] += v2.w;
            a3[0] += v3.x; a3[1] += v3.y; a3[2] += v3.z; a3[3] += v3.w;
        }
        for (; j < e; j += MPI) {
            float4 v = *(const float4*)(sp + (size_t)idx[j] * C + cbase);
            a0[0] += v.x; a0[1] += v.y; a0[2] += v.z; a0[3] += v.w;
        }
    }

    float acc[CPL];
#pragma unroll
    for (int k = 0; k < CPL; ++k) acc[k] = (a0[k] + a1[k]) + (a2[k] + a3[k]);

#pragma unroll
    for (int st = LPR; st < 64; st <<= 1)
#pragma unroll
        for (int k = 0; k < CPL; ++k)
            acc[k] += __shfl_xor(acc[k], st);

    if (lane < LPR) {
        const float inv = 1.f / fmaxf((float)(e - b), 1.f);
        float vout[CPL];
#pragma unroll
        for (int k = 0; k < CPL; ++k) {
            float v = acc[k] * inv;
            if constexpr (DORELU) v = fmaxf(v, 0.f);
            vout[k] = v;
        }
        const size_t obase = (size_t)s * C + cbase;
        if constexpr (EPI == 0 || EPI == 3) {
            float* dp = dstf + (size_t)sign * dstf_stride + obase;
            *(float4*)dp       = make_float4(vout[0], vout[1], vout[2], vout[3]);
            if constexpr (CPL == 8)
                *(float4*)(dp + 4) = make_float4(vout[4], vout[5], vout[6], vout[7]);
        }
        if constexpr (EPI == 1 || EPI == 3) {
            ushort_t* bp = dB + (size_t)sign * dB_stride + obase;
            short4b h0, h1;
#pragma unroll
            for (int k = 0; k < 4; ++k) h0[k] = (short)f2bf_rne(vout[k]);
            *(short4b*)bp = h0;
            if constexpr (CPL == 8) {
#pragma unroll
                for (int k = 0; k < 4; ++k) h1[k] = (short)f2bf_rne(vout[4 + k]);
                *(short4b*)(bp + 4) = h1;
            }
        }
    }
}

extern "C" void kernel_launch(void* const* d_in, const int* in_sizes, int n_in,
                              void* d_out, int out_size, void* d_ws, size_t ws_size,
                              hipStream_t stream)
{
    const float* m_emb = (const float*)d_in[0];
    const int*   v_pos = (const int*)d_in[1];
    const int*   e_pos = (const int*)d_in[2];
    const int*   v_neg = (const int*)d_in[3];
    const int*   e_neg = (const int*)d_in[4];
    const float* W0  = (const float*)d_in[5];
    const float* b0  = (const float*)d_in[6];
    const float* W1  = (const float*)d_in[7];
    const float* b1  = (const float*)d_in[8];
    const float* W2  = (const float*)d_in[9];
    const float* b2  = (const float*)d_in[10];
    const float* Wt1 = (const float*)d_in[11];
    const float* bt1 = (const float*)d_in[12];
    const float* Wt2 = (const float*)d_in[13];
    const float* bt2 = (const float*)d_in[14];
    float* out = (float*)d_out;

    // ---- workspace carve ----
    char* p = (char*)d_ws;
    auto carve = [&](size_t bytes) { char* r = p; p += (bytes + 255) & ~(size_t)255; return r; };
    const size_t NA = (size_t)NNODES * 512;
    ushort_t* regionA = (ushort_t*)carve(NA * 2);                    // 51.2 MB: h0b -> featb
    ushort_t* h1b  = (ushort_t*)carve(NA * 2);                       // 51.2 MB: h1b -> X1b
    ushort_t* Y1b  = (ushort_t*)carve((size_t)2 * NEDGES * 256 * 2); // 102.4 MB
    ushort_t* Xt1b = (ushort_t*)carve((size_t)NNODES * 256 * 2);     // 25.6 MB
    ushort_t* Xt2b = (ushort_t*)carve((size_t)2 * NNODES * 128 * 2); // 25.6 MB
    ushort_t* Y2b  = (ushort_t*)carve((size_t)2 * NEDGES * 128 * 2); // 51.2 MB

    ushort_t* h0b   = regionA;
    ushort_t* featb = regionA;               // G2 output overwrites h0
    ushort_t* X1b   = h1b;                   // [2*50000][256]; h1 dead after G2

    ushort_t* W0t  = (ushort_t*)carve((size_t)512 * 2816 * 2);
    ushort_t* W1t  = (ushort_t*)carve((size_t)512 * 512 * 2);
    ushort_t* W2t  = (ushort_t*)carve((size_t)512 * 512 * 2);
    ushort_t* Wt1t = (ushort_t*)carve((size_t)256 * 512 * 2);
    ushort_t* Wt2t = (ushort_t*)carve((size_t)128 * 256 * 2);
    int* e_off  = (int*)carve((size_t)2 * (NEDGES + 1) * 4);
    int* v_off  = (int*)carve((size_t)2 * (NNODES + 1) * 4);
    int* e_by_v = (int*)carve((size_t)2 * NP * 4);
    int* v_cnt  = (int*)carve((size_t)2 * NNODES * 4);

    const int MB = (NNODES + 127) / 128;       // 391
    const int MB2 = (2 * NNODES + 127) / 128;  // 782

    // ---- fused prologue: weight prep + CSR pass 1 ----
    hipMemsetAsync(v_cnt, 0, (size_t)2 * NNODES * 4, stream);
    prep_csr<<<4128, 256, 0, stream>>>(
        W0, W1, W2, Wt1, Wt2,
        W0t, W1t, W2t, Wt1t, Wt2t,
        e_pos, e_neg, v_pos, v_neg, e_off, v_cnt);
    exscan2<<<2, 1024, 0, stream>>>(v_cnt, v_off);
    scatter_both<<<dim3(1024, 2), 256, 0, stream>>>(v_pos, v_neg, e_pos, e_neg,
                                                    v_off, v_cnt, e_by_v);

    // ---- MLP: wide (BN=256) kernels ----
    gemm_wide<true, true, 1><<<dim3(2, MB), 512, 0, stream>>>(
        m_emb, nullptr, W0t, b0, nullptr, h0b, NNODES, 512, 2816);
    gemm_wide<false, true, 1><<<dim3(2, MB), 512, 0, stream>>>(
        nullptr, h0b, W1t, b1, nullptr, h1b, NNODES, 512, 512);
    gemm_wide<false, false, 1><<<dim3(2, MB), 512, 0, stream>>>(
        nullptr, h1b, W2t, b2, nullptr, featb, NNODES, 512, 512);

    // ---- layer-1 dense (shared by both signs) ----
    gemm_wide<false, false, 1><<<dim3(1, MB), 512, 0, stream>>>(
        nullptr, featb, Wt1t, bt1, nullptr, Xt1b, NNODES, 256, 512);

    // ---- layer-1 aggregation, both signs ----
    seg_mean2<true, 256, false, 1><<<dim3(NEDGES / 4, 2), 256, 0, stream>>>(
        Xt1b, 0, v_pos, v_neg, e_off, NEDGES + 1,
        nullptr, 0, Y1b, (long long)NEDGES * 256, NEDGES);
    seg_mean2<true, 256, true, 1><<<dim3(NNODES / 4, 2), 256, 0, stream>>>(
        Y1b, (long long)NEDGES * 256, e_by_v, e_by_v + NP, v_off, NNODES + 1,
        nullptr, 0, X1b, (long long)NNODES * 256, NNODES);

    // ---- layer-2 dense: one GEMM over both signs (M = 100000), narrow ----
    gemm_bf1<false, false, 1><<<dim3(1, MB2), 256, 0, stream>>>(
        nullptr, X1b, Wt2t, bt2, nullptr, Xt2b, 2 * NNODES, 128, 256);

    // ---- layer-2 aggregation, both signs ----
    // out layout: X1 @0, X2 @6.4M, Y_pos @12.8M, Y_neg @25.6M
    seg_mean2<true, 128, false, 3><<<dim3(NEDGES / 4, 2), 256, 0, stream>>>(
        Xt2b, (long long)NNODES * 128, v_pos, v_neg, e_off, NEDGES + 1,
        out + 12800000, 12800000LL, Y2b, (long long)NEDGES * 128, NEDGES);
    seg_mean2<true, 128, false, 0><<<dim3(NNODES / 4, 2), 256, 0, stream>>>(
        Y2b, (long long)NEDGES * 128, e_by_v, e_by_v + NP, v_off, NNODES + 1,
        out, 6400000LL, nullptr, 0, NNODES);
}

// Round 16
// 1687.310 us; speedup vs baseline: 2.2398x; 2.2398x over previous
//
#include <hip/hip_runtime.h>

#define NP 1600000
#define NNODES 50000
#define NEDGES 100000

typedef short bf16x8 __attribute__((ext_vector_type(8)));
typedef short short4b __attribute__((ext_vector_type(4)));
typedef float f32x4 __attribute__((ext_vector_type(4)));
typedef unsigned short ushort_t;

static __device__ __forceinline__ ushort_t f2bf_rne(float f) {
    __bf16 b = (__bf16)f;
    return __builtin_bit_cast(ushort_t, b);
}
static __device__ __forceinline__ float bf2f(ushort_t h) {
    union { float f; unsigned int u; } v; v.u = ((unsigned int)h) << 16;
    return v.f;
}
static __device__ __forceinline__ void addbf8(float* a, uint4 u) {
    unsigned int uu[4] = {u.x, u.y, u.z, u.w};
#pragma unroll
    for (int q = 0; q < 4; ++q) {
        union { float f; unsigned int v; } lo, hi;
        lo.v = uu[q] << 16; hi.v = uu[q] & 0xffff0000u;
        a[2 * q]     += lo.f;
        a[2 * q + 1] += hi.f;
    }
}

static __device__ __forceinline__ void gload_lds16(const void* g, void* lds) {
    __builtin_amdgcn_global_load_lds(
        (const __attribute__((address_space(1))) unsigned int*)g,
        (__attribute__((address_space(3))) unsigned int*)lds, 16, 0, 0);
}

// ---------------- WIDE single-bf16 MFMA GEMM: BM=128, BN=256, 512 thr -------
// Same 2-barrier schedule as the narrow kernel; 8 waves (2 row x 4 col of
// 64x64) -> 128 MFMA per block-tile vs 64, amortizing per-tile barrier+drain.
// __launch_bounds__(512,4): 128-VGPR cap (R15's (512,6)=85 cap SPILLED:
// VGPR=40, 4.3GB scratch writes). 2 blocks/CU, 16 waves/CU.
// A [M,K]: f32 (in-kernel cvt, AF32) or bf16 (gload_lds). B^T [N,K] bf16.
// EPI: 0 f32 out, 1 bf16 out.
template<bool AF32, bool DORELU, int EPI>
__global__ __launch_bounds__(512, 4) void gemm_wide(
    const float* __restrict__ Af, const ushort_t* __restrict__ Ab,
    const ushort_t* __restrict__ Bth,
    const float* __restrict__ bias,
    float* __restrict__ Cf, ushort_t* __restrict__ Cb,
    int M, int N, int K)
{
    __shared__ ushort_t As [4][129][8];   // 128 A rows
    __shared__ ushort_t BsH[4][257][8];   // 256 B rows (N-cols)

    const int tid = threadIdx.x;
    const int wid = tid >> 6;             // 0..7
    const int lane = tid & 63;

    // bijective XCD-chunked swizzle
    const int nwg = gridDim.x * gridDim.y;
    const int wg  = blockIdx.y * gridDim.x + blockIdx.x;
    const int q = nwg >> 3, r = nwg & 7;
    const int xcd = wg & 7, loc = wg >> 3;
    const int swz = (xcd < r) ? (xcd * (q + 1) + loc)
                              : (r * (q + 1) + (xcd - r) * q + loc);
    const int bn0 = (int)(swz % gridDim.x) * 256;
    const int bm0 = (int)(swz / gridDim.x) * 128;

    const int wrow0 = (wid >> 2) * 64;    // 0 or 64
    const int wcol0 = (wid & 3) * 64;     // 0..192
    const int kgl = lane >> 4;
    const int r16 = lane & 15;

    f32x4 acc[4][4];
#pragma unroll
    for (int i = 0; i < 4; ++i)
#pragma unroll
        for (int j = 0; j < 4; ++j) acc[i][j] = (f32x4)0.f;

    const int nk = K >> 5;

    // AF32 A-staging geometry: 128 rows x 8 quads, 512 threads -> 2 quads each
    const int a_kq   = tid & 7;
    const int a_row0 = tid >> 3;          // 0..63; rows = a_row0 + cch*64
    const float* aBase[2];
    float4 aPre[2];
    if constexpr (AF32) {
#pragma unroll
        for (int cch = 0; cch < 2; ++cch) {
            int row = cch * 64 + a_row0;
            int rr = bm0 + row; if (rr > M - 1) rr = M - 1;
            aBase[cch] = Af + (size_t)rr * K + a_kq * 4;
            aPre[cch] = *(const float4*)(aBase[cch]);   // tile 0
        }
    }

    for (int kt = 0; kt < nk; ++kt) {
        __syncthreads();
        // ---- stage B: 256 rows x 4 kg-planes ----
#pragma unroll
        for (int h = 0; h < 2; ++h) {
            int row0 = (wid >> 2) * 128 + h * 64;
            int cc = bn0 + row0 + lane;
            gload_lds16(Bth + (size_t)cc * K + kt * 32 + (wid & 3) * 8,
                        &BsH[wid & 3][row0][0]);
        }
        // ---- stage A ----
        if constexpr (AF32) {
#pragma unroll
            for (int cch = 0; cch < 2; ++cch) {
                int row = cch * 64 + a_row0;
                float4 v = aPre[cch];
                short4b hi;
                hi[0] = (short)f2bf_rne(v.x); hi[1] = (short)f2bf_rne(v.y);
                hi[2] = (short)f2bf_rne(v.z); hi[3] = (short)f2bf_rne(v.w);
                int kg = a_kq >> 1, j0 = (a_kq & 1) * 4;
                *(short4b*)&As[kg][row][j0] = hi;
            }
        } else {
            int rr = bm0 + (wid >> 2) * 64 + lane; if (rr > M - 1) rr = M - 1;
            gload_lds16(Ab + (size_t)rr * K + kt * 32 + (wid & 3) * 8,
                        &As[wid & 3][(wid >> 2) * 64][0]);
        }
        __syncthreads();

        // issue next A f32 loads NOW; latency hides under MFMA
        if constexpr (AF32) {
            if (kt + 1 < nk) {
#pragma unroll
                for (int cch = 0; cch < 2; ++cch)
                    aPre[cch] = *(const float4*)(aBase[cch] + (kt + 1) * 32);
            }
        }

        bf16x8 ah[4], bh[4];
#pragma unroll
        for (int mi = 0; mi < 4; ++mi)
            ah[mi] = *(const bf16x8*)&As[kgl][wrow0 + mi * 16 + r16][0];
#pragma unroll
        for (int ni = 0; ni < 4; ++ni)
            bh[ni] = *(const bf16x8*)&BsH[kgl][wcol0 + ni * 16 + r16][0];
#pragma unroll
        for (int mi = 0; mi < 4; ++mi)
#pragma unroll
            for (int ni = 0; ni < 4; ++ni)
                acc[mi][ni] = __builtin_amdgcn_mfma_f32_16x16x32_bf16(ah[mi], bh[ni], acc[mi][ni], 0, 0, 0);
    }

    // ---- epilogue: C/D layout col=lane&15 (N), row=(lane>>4)*4+reg (M) ----
    const int rg4 = (lane >> 4) * 4;
#pragma unroll
    for (int ni = 0; ni < 4; ++ni) {
        int gcol = bn0 + wcol0 + ni * 16 + r16;
        float bb = bias[gcol];
#pragma unroll
        for (int mi = 0; mi < 4; ++mi)
#pragma unroll
            for (int rg = 0; rg < 4; ++rg) {
                int grow = bm0 + wrow0 + mi * 16 + rg4 + rg;
                if (grow < M) {
                    float v = acc[mi][ni][rg] + bb;
                    if constexpr (DORELU) v = fmaxf(v, 0.f);
                    if constexpr (EPI == 0) Cf[(size_t)grow * N + gcol] = v;
                    else                    Cb[(size_t)grow * N + gcol] = f2bf_rne(v);
                }
            }
    }
}

// ---------------- narrow kernel (BN=128) — kept for Gt2 (N=128) -------------
template<bool AF32, bool DORELU, int EPI>
__global__ __launch_bounds__(256, 3) void gemm_bf1(
    const float* __restrict__ Af, const ushort_t* __restrict__ Ab,
    const ushort_t* __restrict__ Bth,
    const float* __restrict__ bias,
    float* __restrict__ Cf, ushort_t* __restrict__ Cb,
    int M, int N, int K)
{
    __shared__ ushort_t As [4][129][8];
    __shared__ ushort_t BsH[4][129][8];

    const int tid = threadIdx.x;
    const int wid = tid >> 6;
    const int lane = tid & 63;

    const int nwg = gridDim.x * gridDim.y;
    const int wg  = blockIdx.y * gridDim.x + blockIdx.x;
    const int q = nwg >> 3, r = nwg & 7;
    const int xcd = wg & 7, loc = wg >> 3;
    const int swz = (xcd < r) ? (xcd * (q + 1) + loc)
                              : (r * (q + 1) + (xcd - r) * q + loc);
    const int bn0 = (int)(swz % gridDim.x) * 128;
    const int bm0 = (int)(swz / gridDim.x) * 128;

    const int wrow0 = (wid >> 1) * 64;
    const int wcol0 = (wid & 1) * 64;
    const int kgl = lane >> 4;
    const int r16 = lane & 15;

    f32x4 acc[4][4];
#pragma unroll
    for (int i = 0; i < 4; ++i)
#pragma unroll
        for (int j = 0; j < 4; ++j) acc[i][j] = (f32x4)0.f;

    const int nk = K >> 5;

    const int a_kq   = tid & 7;
    const int a_row0 = tid >> 3;
    const float* aBase[4];
    float4 aPre[4];
    if constexpr (AF32) {
#pragma unroll
        for (int cch = 0; cch < 4; ++cch) {
            int row = cch * 32 + a_row0;
            int rr = bm0 + row; if (rr > M - 1) rr = M - 1;
            aBase[cch] = Af + (size_t)rr * K + a_kq * 4;
            aPre[cch] = *(const float4*)(aBase[cch]);
        }
    }

    for (int kt = 0; kt < nk; ++kt) {
        __syncthreads();
#pragma unroll
        for (int h = 0; h < 2; ++h) {
            int cc = bn0 + h * 64 + lane;
            gload_lds16(Bth + (size_t)cc * K + kt * 32 + wid * 8,
                        &BsH[wid][h * 64][0]);
        }
        if constexpr (AF32) {
#pragma unroll
            for (int cch = 0; cch < 4; ++cch) {
                int row = cch * 32 + a_row0;
                float4 v = aPre[cch];
                short4b hi;
                hi[0] = (short)f2bf_rne(v.x); hi[1] = (short)f2bf_rne(v.y);
                hi[2] = (short)f2bf_rne(v.z); hi[3] = (short)f2bf_rne(v.w);
                int kg = a_kq >> 1, j0 = (a_kq & 1) * 4;
                *(short4b*)&As[kg][row][j0] = hi;
            }
        } else {
#pragma unroll
            for (int h = 0; h < 2; ++h) {
                int rr = bm0 + h * 64 + lane; if (rr > M - 1) rr = M - 1;
                gload_lds16(Ab + (size_t)rr * K + kt * 32 + wid * 8,
                            &As[wid][h * 64][0]);
            }
        }
        __syncthreads();

        if constexpr (AF32) {
            if (kt + 1 < nk) {
#pragma unroll
                for (int cch = 0; cch < 4; ++cch)
                    aPre[cch] = *(const float4*)(aBase[cch] + (kt + 1) * 32);
            }
        }

        bf16x8 ah[4], bh[4];
#pragma unroll
        for (int mi = 0; mi < 4; ++mi)
            ah[mi] = *(const bf16x8*)&As[kgl][wrow0 + mi * 16 + r16][0];
#pragma unroll
        for (int ni = 0; ni < 4; ++ni)
            bh[ni] = *(const bf16x8*)&BsH[kgl][wcol0 + ni * 16 + r16][0];
#pragma unroll
        for (int mi = 0; mi < 4; ++mi)
#pragma unroll
            for (int ni = 0; ni < 4; ++ni)
                acc[mi][ni] = __builtin_amdgcn_mfma_f32_16x16x32_bf16(ah[mi], bh[ni], acc[mi][ni], 0, 0, 0);
    }

    const int rg4 = (lane >> 4) * 4;
#pragma unroll
    for (int ni = 0; ni < 4; ++ni) {
        int gcol = bn0 + wcol0 + ni * 16 + r16;
        float bb = bias[gcol];
#pragma unroll
        for (int mi = 0; mi < 4; ++mi)
#pragma unroll
            for (int rg = 0; rg < 4; ++rg) {
                int grow = bm0 + wrow0 + mi * 16 + rg4 + rg;
                if (grow < M) {
                    float v = acc[mi][ni][rg] + bb;
                    if constexpr (DORELU) v = fmaxf(v, 0.f);
                    if constexpr (EPI == 0) Cf[(size_t)grow * N + gcol] = v;
                    else                    Cb[(size_t)grow * N + gcol] = f2bf_rne(v);
                }
            }
    }
}

// ------- fused prologue: weight transpose (single bf16) + CSR pass 1 -------
__global__ __launch_bounds__(256) void prep_csr(
    const float* __restrict__ W0, const float* __restrict__ W1,
    const float* __restrict__ W2, const float* __restrict__ Wt1,
    const float* __restrict__ Wt2,
    ushort_t* __restrict__ W0t, ushort_t* __restrict__ W1t,
    ushort_t* __restrict__ W2t, ushort_t* __restrict__ Wt1t,
    ushort_t* __restrict__ Wt2t,
    const int* __restrict__ ePos, const int* __restrict__ eNeg,
    const int* __restrict__ vPos, const int* __restrict__ vNeg,
    int* __restrict__ e_off, int* __restrict__ v_cnt)
{
    const int bsel = blockIdx.x;
    if (bsel >= 2080) {
        const int rel = bsel - 2080;
        const int sign = rel >> 10;
        const int* e_idx = sign ? eNeg : ePos;
        const int* v_idx = sign ? vNeg : vPos;
        int* o  = e_off + sign * (NEDGES + 1);
        int* vc = v_cnt + sign * NNODES;
        int i = (rel & 1023) * 256 + threadIdx.x;
        const int stride = 1024 * 256;
        for (; i < NP; i += stride) {
            int cur = e_idx[i];
            int prev = (i > 0) ? e_idx[i - 1] : -1;
            for (int e = prev + 1; e <= cur; ++e) o[e] = i;
            if (i == NP - 1)
                for (int e = cur + 1; e <= NEDGES; ++e) o[e] = NP;
            atomicAdd(&vc[v_idx[i]], 1);
        }
        return;
    }
    const float* W; ushort_t* H; int K, N, nx, rel;
    if (bsel < 1408)      { W = W0;  H = W0t;  K = 2816; N = 512; nx = 16; rel = bsel; }
    else if (bsel < 1664) { W = W1;  H = W1t;  K = 512;  N = 512; nx = 16; rel = bsel - 1408; }
    else if (bsel < 1920) { W = W2;  H = W2t;  K = 512;  N = 512; nx = 16; rel = bsel - 1664; }
    else if (bsel < 2048) { W = Wt1; H = Wt1t; K = 512;  N = 256; nx = 8;  rel = bsel - 1920; }
    else                  { W = Wt2; H = Wt2t; K = 256;  N = 128; nx = 4;  rel = bsel - 2048; }
    const int n0 = (rel % nx) * 32, k0 = (rel / nx) * 32;

    __shared__ float T[32][33];
    const int c = threadIdx.x & 31, r8 = threadIdx.x >> 5;
#pragma unroll
    for (int i = 0; i < 4; ++i)
        T[r8 + i * 8][c] = W[(size_t)(k0 + r8 + i * 8) * N + n0 + c];
    __syncthreads();
#pragma unroll
    for (int i = 0; i < 4; ++i) {
        int nr = r8 + i * 8;
        H[(size_t)(n0 + nr) * K + k0 + c] = f2bf_rne(T[c][nr]);
    }
}

__global__ __launch_bounds__(1024) void exscan2(const int* __restrict__ cnt,
                                                int* __restrict__ off)
{
    const int sign = blockIdx.x;
    const int* c = cnt + sign * NNODES;
    int* o = off + sign * (NNODES + 1);
    __shared__ int sums[1024];
    const int t = threadIdx.x;
    const int per = (NNODES + 1023) >> 10;
    const int b = t * per;
    const int e = min(b + per, NNODES);
    int s = 0;
    for (int i = b; i < e; ++i) s += c[i];
    sums[t] = s;
    __syncthreads();
    for (int d = 1; d < 1024; d <<= 1) {
        int v = (t >= d) ? sums[t - d] : 0;
        __syncthreads();
        sums[t] += v;
        __syncthreads();
    }
    int run = (t > 0) ? sums[t - 1] : 0;
    for (int i = b; i < e; ++i) { o[i] = run; run += c[i]; }
    if (t == 1023) o[NNODES] = run;
}

__global__ void scatter_both(const int* __restrict__ vPos, const int* __restrict__ vNeg,
                             const int* __restrict__ ePos, const int* __restrict__ eNeg,
                             const int* __restrict__ v_off, int* __restrict__ v_cnt,
                             int* __restrict__ e_by_v)
{
    const int sign = blockIdx.y;
    const int* v_idx = sign ? vNeg : vPos;
    const int* e_idx = sign ? eNeg : ePos;
    const int* vo = v_off + sign * (NNODES + 1);
    int* vc = v_cnt + sign * NNODES;
    int* ebv = e_by_v + sign * NP;
    int i = blockIdx.x * blockDim.x + threadIdx.x;
    int stride = gridDim.x * blockDim.x;
    for (; i < NP; i += stride) {
        int v = v_idx[i];
        int pos = atomicSub(&vc[v], 1) - 1;
        ebv[vo[v] + pos] = e_idx[i];
    }
}

// ---------------- segment mean, dual-sign, 16B/lane, 4-wide gather ----------
// EPI: 0 f32 out, 1 bf16 out, 3 f32 out + bf16 shadow.  Vectorized stores.
template<bool SRCBF, int C, bool DORELU, int EPI>
__global__ __launch_bounds__(256) void seg_mean2(
    const void* __restrict__ src, long long src_stride,
    const int* __restrict__ idx0, const int* __restrict__ idx1,
    const int* __restrict__ off_base, int off_stride,
    float* __restrict__ dstf, long long dstf_stride,
    ushort_t* __restrict__ dB, long long dB_stride,
    int nseg)
{
    constexpr int ES  = SRCBF ? 2 : 4;
    constexpr int LPR = (C * ES) / 16;
    constexpr int MPI = 64 / LPR;
    constexpr int CPL = 16 / ES;

    const int sign = blockIdx.y;
    const int* idx = sign ? idx1 : idx0;
    const int* off = off_base + (size_t)sign * off_stride;

    const int wave = threadIdx.x >> 6, lane = threadIdx.x & 63;
    const int s = blockIdx.x * 4 + wave;
    if (s >= nseg) return;
    const int b = off[s], e = off[s + 1];
    const int sub = lane / LPR;
    const int cbase = (lane % LPR) * CPL;

    float a0[CPL], a1[CPL], a2[CPL], a3[CPL];
#pragma unroll
    for (int k = 0; k < CPL; ++k) { a0[k] = 0.f; a1[k] = 0.f; a2[k] = 0.f; a3[k] = 0.f; }

    int j = b + sub;
    if constexpr (SRCBF) {
        const ushort_t* sp = (const ushort_t*)src + (size_t)sign * src_stride;
        for (; j + 3 * MPI < e; j += 4 * MPI) {
            int i0 = idx[j], i1 = idx[j + MPI], i2 = idx[j + 2 * MPI], i3 = idx[j + 3 * MPI];
            uint4 u0 = *(const uint4*)(sp + (size_t)i0 * C + cbase);
            uint4 u1 = *(const uint4*)(sp + (size_t)i1 * C + cbase);
            uint4 u2 = *(const uint4*)(sp + (size_t)i2 * C + cbase);
            uint4 u3 = *(const uint4*)(sp + (size_t)i3 * C + cbase);
            addbf8(a0, u0); addbf8(a1, u1); addbf8(a2, u2); addbf8(a3, u3);
        }
        for (; j < e; j += MPI) {
            uint4 u = *(const uint4*)(sp + (size_t)idx[j] * C + cbase);
            addbf8(a0, u);
        }
    } else {
        const float* sp = (const float*)src + (size_t)sign * src_stride;
        for (; j + 3 * MPI < e; j += 4 * MPI) {
            int i0 = idx[j], i1 = idx[j + MPI], i2 = idx[j + 2 * MPI], i3 = idx[j + 3 * MPI];
            float4 v0 = *(const float4*)(sp + (size_t)i0 * C + cbase);
            float4 v1 = *(const float4*)(sp + (size_t)i1 * C + cbase);
            float4 v2 = *(const float4*)(sp + (size_t)i2 * C + cbase);
            float4 v3 = *(const float4*)(sp + (size_t)i3 * C + cbase);
            a0[0] += v0.x; a0[1] += v0.y; a0[2] += v0.z; a0[3] += v0.w;
            a1[0] += v1.x; a1[1] += v1.y; a1[2] += v1.z; a1[3] += v1.w;
            a2[0] += v2.x; a2[1] += v2.y; a2[2] += v2.z; a2[3] += v2.w;
            a3[0] += v3.x; a3[1] += v3.y; a3[2] += v3.z; a3[3] += v3.w;
        }
        for (; j < e; j += MPI) {
            float4 v = *(const float4*)(sp + (size_t)idx[j] * C + cbase);
            a0[0] += v.x; a0[1] += v.y; a0[2] += v.z; a0[3] += v.w;
        }
    }

    float acc[CPL];
#pragma unroll
    for (int k = 0; k < CPL; ++k) acc[k] = (a0[k] + a1[k]) + (a2[k] + a3[k]);

#pragma unroll
    for (int st = LPR; st < 64; st <<= 1)
#pragma unroll
        for (int k = 0; k < CPL; ++k)
            acc[k] += __shfl_xor(acc[k], st);

    if (lane < LPR) {
        const float inv = 1.f / fmaxf((float)(e - b), 1.f);
        float vout[CPL];
#pragma unroll
        for (int k = 0; k < CPL; ++k) {
            float v = acc[k] * inv;
            if constexpr (DORELU) v = fmaxf(v, 0.f);
            vout[k] = v;
        }
        const size_t obase = (size_t)s * C + cbase;
        if constexpr (EPI == 0 || EPI == 3) {
            float* dp = dstf + (size_t)sign * dstf_stride + obase;
            *(float4*)dp       = make_float4(vout[0], vout[1], vout[2], vout[3]);
            if constexpr (CPL == 8)
                *(float4*)(dp + 4) = make_float4(vout[4], vout[5], vout[6], vout[7]);
        }
        if constexpr (EPI == 1 || EPI == 3) {
            ushort_t* bp = dB + (size_t)sign * dB_stride + obase;
            short4b h0, h1;
#pragma unroll
            for (int k = 0; k < 4; ++k) h0[k] = (short)f2bf_rne(vout[k]);
            *(short4b*)bp = h0;
            if constexpr (CPL == 8) {
#pragma unroll
                for (int k = 0; k < 4; ++k) h1[k] = (short)f2bf_rne(vout[4 + k]);
                *(short4b*)(bp + 4) = h1;
            }
        }
    }
}

extern "C" void kernel_launch(void* const* d_in, const int* in_sizes, int n_in,
                              void* d_out, int out_size, void* d_ws, size_t ws_size,
                              hipStream_t stream)
{
    const float* m_emb = (const float*)d_in[0];
    const int*   v_pos = (const int*)d_in[1];
    const int*   e_pos = (const int*)d_in[2];
    const int*   v_neg = (const int*)d_in[3];
    const int*   e_neg = (const int*)d_in[4];
    const float* W0  = (const float*)d_in[5];
    const float* b0  = (const float*)d_in[6];
    const float* W1  = (const float*)d_in[7];
    const float* b1  = (const float*)d_in[8];
    const float* W2  = (const float*)d_in[9];
    const float* b2  = (const float*)d_in[10];
    const float* Wt1 = (const float*)d_in[11];
    const float* bt1 = (const float*)d_in[12];
    const float* Wt2 = (const float*)d_in[13];
    const float* bt2 = (const float*)d_in[14];
    float* out = (float*)d_out;

    // ---- workspace carve ----
    char* p = (char*)d_ws;
    auto carve = [&](size_t bytes) { char* r = p; p += (bytes + 255) & ~(size_t)255; return r; };
    const size_t NA = (size_t)NNODES * 512;
    ushort_t* regionA = (ushort_t*)carve(NA * 2);                    // 51.2 MB: h0b -> featb
    ushort_t* h1b  = (ushort_t*)carve(NA * 2);                       // 51.2 MB: h1b -> X1b
    ushort_t* Y1b  = (ushort_t*)carve((size_t)2 * NEDGES * 256 * 2); // 102.4 MB
    ushort_t* Xt1b = (ushort_t*)carve((size_t)NNODES * 256 * 2);     // 25.6 MB
    ushort_t* Xt2b = (ushort_t*)carve((size_t)2 * NNODES * 128 * 2); // 25.6 MB
    ushort_t* Y2b  = (ushort_t*)carve((size_t)2 * NEDGES * 128 * 2); // 51.2 MB

    ushort_t* h0b   = regionA;
    ushort_t* featb = regionA;               // G2 output overwrites h0
    ushort_t* X1b   = h1b;                   // [2*50000][256]; h1 dead after G2

    ushort_t* W0t  = (ushort_t*)carve((size_t)512 * 2816 * 2);
    ushort_t* W1t  = (ushort_t*)carve((size_t)512 * 512 * 2);
    ushort_t* W2t  = (ushort_t*)carve((size_t)512 * 512 * 2);
    ushort_t* Wt1t = (ushort_t*)carve((size_t)256 * 512 * 2);
    ushort_t* Wt2t = (ushort_t*)carve((size_t)128 * 256 * 2);
    int* e_off  = (int*)carve((size_t)2 * (NEDGES + 1) * 4);
    int* v_off  = (int*)carve((size_t)2 * (NNODES + 1) * 4);
    int* e_by_v = (int*)carve((size_t)2 * NP * 4);
    int* v_cnt  = (int*)carve((size_t)2 * NNODES * 4);

    const int MB = (NNODES + 127) / 128;       // 391
    const int MB2 = (2 * NNODES + 127) / 128;  // 782

    // ---- fused prologue: weight prep + CSR pass 1 ----
    hipMemsetAsync(v_cnt, 0, (size_t)2 * NNODES * 4, stream);
    prep_csr<<<4128, 256, 0, stream>>>(
        W0, W1, W2, Wt1, Wt2,
        W0t, W1t, W2t, Wt1t, Wt2t,
        e_pos, e_neg, v_pos, v_neg, e_off, v_cnt);
    exscan2<<<2, 1024, 0, stream>>>(v_cnt, v_off);
    scatter_both<<<dim3(1024, 2), 256, 0, stream>>>(v_pos, v_neg, e_pos, e_neg,
                                                    v_off, v_cnt, e_by_v);

    // ---- MLP: wide (BN=256) kernels ----
    gemm_wide<true, true, 1><<<dim3(2, MB), 512, 0, stream>>>(
        m_emb, nullptr, W0t, b0, nullptr, h0b, NNODES, 512, 2816);
    gemm_wide<false, true, 1><<<dim3(2, MB), 512, 0, stream>>>(
        nullptr, h0b, W1t, b1, nullptr, h1b, NNODES, 512, 512);
    gemm_wide<false, false, 1><<<dim3(2, MB), 512, 0, stream>>>(
        nullptr, h1b, W2t, b2, nullptr, featb, NNODES, 512, 512);

    // ---- layer-1 dense (shared by both signs) ----
    gemm_wide<false, false, 1><<<dim3(1, MB), 512, 0, stream>>>(
        nullptr, featb, Wt1t, bt1, nullptr, Xt1b, NNODES, 256, 512);

    // ---- layer-1 aggregation, both signs ----
    seg_mean2<true, 256, false, 1><<<dim3(NEDGES / 4, 2), 256, 0, stream>>>(
        Xt1b, 0, v_pos, v_neg, e_off, NEDGES + 1,
        nullptr, 0, Y1b, (long long)NEDGES * 256, NEDGES);
    seg_mean2<true, 256, true, 1><<<dim3(NNODES / 4, 2), 256, 0, stream>>>(
        Y1b, (long long)NEDGES * 256, e_by_v, e_by_v + NP, v_off, NNODES + 1,
        nullptr, 0, X1b, (long long)NNODES * 256, NNODES);

    // ---- layer-2 dense: one GEMM over both signs (M = 100000), narrow ----
    gemm_bf1<false, false, 1><<<dim3(1, MB2), 256, 0, stream>>>(
        nullptr, X1b, Wt2t, bt2, nullptr, Xt2b, 2 * NNODES, 128, 256);

    // ---- layer-2 aggregation, both signs ----
    // out layout: X1 @0, X2 @6.4M, Y_pos @12.8M, Y_neg @25.6M
    seg_mean2<true, 128, false, 3><<<dim3(NEDGES / 4, 2), 256, 0, stream>>>(
        Xt2b, (long long)NNODES * 128, v_pos, v_neg, e_off, NEDGES + 1,
        out + 12800000, 12800000LL, Y2b, (long long)NEDGES * 128, NEDGES);
    seg_mean2<true, 128, false, 0><<<dim3(NNODES / 4, 2), 256, 0, stream>>>(
        Y2b, (long long)NEDGES * 128, e_by_v, e_by_v + NP, v_off, NNODES + 1,
        out, 6400000LL, nullptr, 0, NNODES);
}